// Round 12
// baseline (164.001 us; speedup 1.0000x reference)
//
#include <hip/hip_runtime.h>
#include <hip/hip_fp16.h>

// ADI diffusion B=16, C=8, S=128, 10 steps. Round 21: 5-dispatch pair fusion.
// r11: 152.7us = ~92 work + ~60 dispatch overhead (o=5.5us x 11). With the
// swizzled phases (w=8.3us), pair redundancy (~3us) < o => fusion pays now.
// head2 = steps 0+1 (16-row trapezoid, raw coeffs) + epilogue writing packed
// coeff fields for steps 2..9 (replaces coef kernel). pairS = 2 steps, the
// intermediate entirely in LDS: P/Q/C = 96 rows x 128 swizzled fp32 =144KB.
// All taps/stores are r11's proven b128/float2 swizzled patterns.

constexpr int S_  = 128;
constexpr float EPSF = 1e-6f;
constexpr int CSS = 8 * 128 * 128;  // points per coeff field

constexpr int P0    = 0;            // 96 rows
constexpr int Q0    = 96 * 128;     // 96 rows
constexpr int C0    = 192 * 128;    // 96 rows
constexpr int ST0   = 96 * 128;     // head: 128 rows overlapping Q + C[0,32)
constexpr int SPOOL = 288 * 128;    // 147456 B

__device__ __forceinline__ int swad4(int r, int b4) {
    return r * 128 + (((b4) ^ (r & 31)) << 2);
}
__device__ __forceinline__ int swadw(int r, int w) {
    return r * 128 + ((((w) >> 2) ^ (r & 31)) << 2) + ((w) & 3);
}

template <int N>
__device__ __forceinline__ void jrunN(const float (&e)[N], const float (&g)[N],
                                      float (&o)[N - 4]) {
    // Jacobi-2 == fixed 5-point formula, stencil radius 2 per output.
    float x1[N];
    #pragma unroll
    for (int i = 1; i <= N - 2; ++i) x1[i] = fmaf(g[i], e[i - 1] + e[i + 1], e[i]);
    #pragma unroll
    for (int i = 2; i <= N - 3; ++i) o[i - 2] = fmaf(g[i], x1[i - 1] + x1[i + 1], e[i]);
}

// gather 16 A-values + 16 C-words for a run (r, wr) from two swizzled regions
#define TAPS_GATHER(REG_A, f, cb)                                              \
    {                                                                          \
        _Pragma("unroll")                                                      \
        for (int i_ = 0; i_ < 4; ++i_) {                                       \
            const int bb_ = 2 * wr - 1 + i_;                                   \
            if (bb_ >= 0 && bb_ < 32) {                                        \
                const float4 va_ = *(const float4*)&sP[(REG_A) + swad4(r, bb_)];\
                const float4 vc_ = *(const float4*)&sP[C0 + swad4(r, bb_)];    \
                f[4*i_+0]=va_.x; f[4*i_+1]=va_.y; f[4*i_+2]=va_.z; f[4*i_+3]=va_.w; \
                cb[4*i_+0]=__float_as_uint(vc_.x); cb[4*i_+1]=__float_as_uint(vc_.y); \
                cb[4*i_+2]=__float_as_uint(vc_.z); cb[4*i_+3]=__float_as_uint(vc_.w); \
            } else {                                                           \
                f[4*i_+0]=f[4*i_+1]=f[4*i_+2]=f[4*i_+3]=0.f;                   \
                cb[4*i_+0]=cb[4*i_+1]=cb[4*i_+2]=cb[4*i_+3]=0u;                \
            }                                                                  \
        }                                                                      \
    }

template <bool LAST>
__global__ __launch_bounds__(512) void pairS_kernel(
    const __half* __restrict__ us, void* __restrict__ udst_,
    const __half2* __restrict__ cfyA, const __half2* __restrict__ cfxA,
    const __half2* __restrict__ cfyB, const __half2* __restrict__ cfxB,
    const float* __restrict__ cm)
{
    __shared__ __align__(16) float sP[SPOOL];
    const int tid = threadIdx.x;
    const int b   = blockIdx.x >> 4;
    const int h0  = (blockIdx.x & 15) << 3;

    // ---- Y-A: 16-in -> 12-out -> P. 512 threads, one (c, w-pair) each.
    {
        const int c = tid >> 6, wp = tid & 63, wb = 2 * wp;
        uint du[16]; uint2 dc[16];
        #pragma unroll
        for (int hh = 0; hh < 16; ++hh) {
            const int gh = h0 - 4 + hh;
            const bool inr = (gh >= 0 && gh < S_);
            const int ghc = inr ? gh : 0;
            du[hh] = inr ? *(const uint*)&us[((b * 8 + c) * S_ + ghc) * S_ + wb] : 0u;
            dc[hh] = *(const uint2*)&cfyA[(c * S_ + ghc) * S_ + wb];
        }
        float o2[2][12];
        #pragma unroll
        for (int s = 0; s < 2; ++s) {
            float e[16], g[16];
            #pragma unroll
            for (int hh = 0; hh < 16; ++hh) {
                const int gh = h0 - 4 + hh;
                const bool inr = (gh >= 0 && gh < S_);
                uint ub = du[hh];
                __half2 hu = *reinterpret_cast<__half2*>(&ub);
                const float dv = s ? __high2float(hu) : __low2float(hu);
                uint cb = s ? dc[hh].y : dc[hh].x;
                const float2 f = __half22float2(*reinterpret_cast<__half2*>(&cb));
                e[hh] = (1.f + f.y) * dv;
                g[hh] = inr ? f.x : 0.f;
            }
            jrunN<16>(e, g, o2[s]);
        }
        #pragma unroll
        for (int i = 0; i < 12; ++i) {
            const int r = c * 12 + i;
            *(float2*)&sP[P0 + r * 128 + (((wp >> 1) ^ (r & 31)) << 2) + 2 * (wp & 1)]
                = make_float2(o2[0][i], o2[1][i]);
        }
    }
    // ---- C-A stage: 96 rows x 32 blk4, 6/thread (packed cfxA -> C)
    {
        const uint* cx = (const uint*)cfxA;
        #pragma unroll
        for (int m = 0; m < 6; ++m) {
            const int task = tid + 512 * m;
            const int r = task >> 5, b4 = task & 31;
            const int c = r / 12, ha = r - c * 12;
            int gh = h0 - 2 + ha; gh = gh < 0 ? 0 : (gh >= S_ ? S_ - 1 : gh);
            const uint4 v = *(const uint4*)&cx[(c * S_ + gh) * S_ + b4 * 4];
            *(float4*)&sP[C0 + swad4(r, b4)] = make_float4(
                __uint_as_float(v.x), __uint_as_float(v.y),
                __uint_as_float(v.z), __uint_as_float(v.w));
        }
    }
    __syncthreads();

    // ---- X1-A: 96 rows x 16 runs, 3/thread; P,C -> Q
    #pragma unroll
    for (int m = 0; m < 3; ++m) {
        const int r  = (tid & 31) + 32 * m;
        const int wr = tid >> 5;
        float f[16]; uint cb[16];
        TAPS_GATHER(P0, f, cb)
        float e[12], g[12];
        #pragma unroll
        for (int j = 0; j < 12; ++j) {
            uint c_ = cb[j + 2];
            const float2 fc = __half22float2(*reinterpret_cast<__half2*>(&c_));
            e[j] = (1.f + fc.y) * f[j + 2];
            g[j] = fc.x;
        }
        float o[8]; jrunN<12>(e, g, o);
        *(float4*)&sP[Q0 + swad4(r, 2 * wr)]     = make_float4(o[0], o[1], o[2], o[3]);
        *(float4*)&sP[Q0 + swad4(r, 2 * wr + 1)] = make_float4(o[4], o[5], o[6], o[7]);
    }
    __syncthreads();
    // ---- mix-A in place on Q: 1536 pts, 3/thread
    {
        float M[64];
        #pragma unroll
        for (int i = 0; i < 64; ++i) M[i] = cm[i];
        #pragma unroll
        for (int m = 0; m < 3; ++m) {
            const int p = tid + 512 * m;
            const int ha = p >> 7, w = p & 127;
            float v[8], o[8];
            #pragma unroll
            for (int c = 0; c < 8; ++c) v[c] = sP[Q0 + swadw(c * 12 + ha, w)];
            #pragma unroll
            for (int dd = 0; dd < 8; ++dd) {
                float a = 0.f;
                #pragma unroll
                for (int c = 0; c < 8; ++c) a = fmaf(M[dd * 8 + c], v[c], a);
                o[dd] = a;
            }
            #pragma unroll
            for (int c = 0; c < 8; ++c) sP[Q0 + swadw(c * 12 + ha, w)] = o[c];
        }
    }
    __syncthreads();
    // ---- X2-A: Q,C -> P (same coeffs)
    #pragma unroll
    for (int m = 0; m < 3; ++m) {
        const int r  = (tid & 31) + 32 * m;
        const int wr = tid >> 5;
        float f[16]; uint cb[16];
        TAPS_GATHER(Q0, f, cb)
        float e[12], g[12];
        #pragma unroll
        for (int j = 0; j < 12; ++j) {
            uint c_ = cb[j + 2];
            const float2 fc = __half22float2(*reinterpret_cast<__half2*>(&c_));
            e[j] = (1.f + fc.y) * f[j + 2];
            g[j] = fc.x;
        }
        float o[8]; jrunN<12>(e, g, o);
        *(float4*)&sP[P0 + swad4(r, 2 * wr)]     = make_float4(o[0], o[1], o[2], o[3]);
        *(float4*)&sP[P0 + swad4(r, 2 * wr + 1)] = make_float4(o[4], o[5], o[6], o[7]);
    }
    __syncthreads();

    // ---- Y-B: 12-in (P) -> 8-out -> Q[0,64)
    {
        const int c = tid >> 6, wp = tid & 63, wb = 2 * wp;
        float2 dp[12]; uint2 dc[12];
        #pragma unroll
        for (int hh = 0; hh < 12; ++hh) {
            const int gh = h0 - 2 + hh;
            const bool inr = (gh >= 0 && gh < S_);
            const int ghc = inr ? gh : 0;
            const int r = c * 12 + hh;
            dp[hh] = *(const float2*)&sP[P0 + r * 128 +
                                         (((wp >> 1) ^ (r & 31)) << 2) + 2 * (wp & 1)];
            dc[hh] = *(const uint2*)&cfyB[(c * S_ + ghc) * S_ + wb];
        }
        float o2[2][8];
        #pragma unroll
        for (int s = 0; s < 2; ++s) {
            float e[12], g[12];
            #pragma unroll
            for (int hh = 0; hh < 12; ++hh) {
                const int gh = h0 - 2 + hh;
                const bool inr = (gh >= 0 && gh < S_);
                const float dv = s ? dp[hh].y : dp[hh].x;
                uint cb = s ? dc[hh].y : dc[hh].x;
                const float2 f = __half22float2(*reinterpret_cast<__half2*>(&cb));
                e[hh] = (1.f + f.y) * dv;
                g[hh] = inr ? f.x : 0.f;
            }
            jrunN<12>(e, g, o2[s]);
        }
        #pragma unroll
        for (int i = 0; i < 8; ++i) {
            const int r = c * 8 + i;
            *(float2*)&sP[Q0 + r * 128 + (((wp >> 1) ^ (r & 31)) << 2) + 2 * (wp & 1)]
                = make_float2(o2[0][i], o2[1][i]);
        }
    }
    // ---- C-B stage: 64 rows x 32 blk4, 4/thread
    {
        const uint* cx = (const uint*)cfxB;
        #pragma unroll
        for (int m = 0; m < 4; ++m) {
            const int task = tid + 512 * m;
            const int r = task >> 5, b4 = task & 31;
            const int c = r >> 3, ho = r & 7;
            const uint4 v = *(const uint4*)&cx[(c * S_ + h0 + ho) * S_ + b4 * 4];
            *(float4*)&sP[C0 + swad4(r, b4)] = make_float4(
                __uint_as_float(v.x), __uint_as_float(v.y),
                __uint_as_float(v.z), __uint_as_float(v.w));
        }
    }
    __syncthreads();

    // ---- X1-B: 64 rows x 16 runs, 2/thread; cache rb/g for X2-B
    float rbk[2][12], gk[2][12], xo[2][8];
    #pragma unroll
    for (int m = 0; m < 2; ++m) {
        const int r  = tid & 63;
        const int wr = (tid >> 6) + 8 * m;
        float f[16]; uint cb[16];
        TAPS_GATHER(Q0, f, cb)
        float e[12];
        #pragma unroll
        for (int j = 0; j < 12; ++j) {
            uint c_ = cb[j + 2];
            const float2 fc = __half22float2(*reinterpret_cast<__half2*>(&c_));
            rbk[m][j] = 1.f + fc.y; gk[m][j] = fc.x;
            e[j] = rbk[m][j] * f[j + 2];
        }
        jrunN<12>(e, gk[m], xo[m]);
    }

    if (LAST) {
        // step 9 final: no mix; xo -> fp32 d_out
        float* ud = (float*)udst_;
        #pragma unroll
        for (int m = 0; m < 2; ++m) {
            const int r  = tid & 63;
            const int wr = (tid >> 6) + 8 * m;
            const int c = r >> 3, ho = r & 7;
            float4* dst4 = (float4*)&ud[((b * 8 + c) * S_ + h0 + ho) * S_ + wr * 8];
            dst4[0] = make_float4(xo[m][0], xo[m][1], xo[m][2], xo[m][3]);
            dst4[1] = make_float4(xo[m][4], xo[m][5], xo[m][6], xo[m][7]);
        }
    } else {
        // park xo -> P[0,64)
        #pragma unroll
        for (int m = 0; m < 2; ++m) {
            const int r  = tid & 63;
            const int wr = (tid >> 6) + 8 * m;
            *(float4*)&sP[P0 + swad4(r, 2 * wr)]     = make_float4(xo[m][0], xo[m][1], xo[m][2], xo[m][3]);
            *(float4*)&sP[P0 + swad4(r, 2 * wr + 1)] = make_float4(xo[m][4], xo[m][5], xo[m][6], xo[m][7]);
        }
        __syncthreads();
        // mix-B in place on P[0,64): 1024 pts, 2/thread
        {
            float M[64];
            #pragma unroll
            for (int i = 0; i < 64; ++i) M[i] = cm[i];
            #pragma unroll
            for (int m = 0; m < 2; ++m) {
                const int p = tid + 512 * m;
                const int ho = p >> 7, w = p & 127;
                float v[8], o[8];
                #pragma unroll
                for (int c = 0; c < 8; ++c) v[c] = sP[P0 + swadw(c * 8 + ho, w)];
                #pragma unroll
                for (int dd = 0; dd < 8; ++dd) {
                    float a = 0.f;
                    #pragma unroll
                    for (int c = 0; c < 8; ++c) a = fmaf(M[dd * 8 + c], v[c], a);
                    o[dd] = a;
                }
                #pragma unroll
                for (int c = 0; c < 8; ++c) sP[P0 + swadw(c * 8 + ho, w)] = o[c];
            }
        }
        __syncthreads();
        // X2-B: P taps + cached coeffs -> fp16 out
        __half* ud = (__half*)udst_;
        #pragma unroll
        for (int m = 0; m < 2; ++m) {
            const int r  = tid & 63;
            const int wr = (tid >> 6) + 8 * m;
            const int c = r >> 3, ho = r & 7;
            float f[16];
            #pragma unroll
            for (int i = 0; i < 4; ++i) {
                const int bb = 2 * wr - 1 + i;
                if (bb >= 0 && bb < 32) {
                    const float4 va = *(const float4*)&sP[P0 + swad4(r, bb)];
                    f[4*i+0]=va.x; f[4*i+1]=va.y; f[4*i+2]=va.z; f[4*i+3]=va.w;
                } else {
                    f[4*i+0]=f[4*i+1]=f[4*i+2]=f[4*i+3]=0.f;
                }
            }
            float e[12];
            #pragma unroll
            for (int j = 0; j < 12; ++j) e[j] = rbk[m][j] * f[j + 2];
            float o[8]; jrunN<12>(e, gk[m], o);
            __half2 q0 = __floats2half2_rn(o[0], o[1]);
            __half2 q1 = __floats2half2_rn(o[2], o[3]);
            __half2 q2 = __floats2half2_rn(o[4], o[5]);
            __half2 q3 = __floats2half2_rn(o[6], o[7]);
            uint4 pk;
            pk.x = *reinterpret_cast<uint*>(&q0);
            pk.y = *reinterpret_cast<uint*>(&q1);
            pk.z = *reinterpret_cast<uint*>(&q2);
            pk.w = *reinterpret_cast<uint*>(&q3);
            *(uint4*)&ud[((b * 8 + c) * S_ + h0 + ho) * S_ + wr * 8] = pk;
        }
    }
}

// ---- head2: steps 0+1 (raw coeffs) + epilogue writing cf fields 2..9 ----
__global__ __launch_bounds__(512) void head2_kernel(
    const float* __restrict__ u0, __half* __restrict__ ud,
    const float* __restrict__ ab, const float* __restrict__ atc,
    const float* __restrict__ bb, const float* __restrict__ btc,
    const float* __restrict__ cm, __half2* __restrict__ cf)
{
    __shared__ __align__(16) float sP[SPOOL];
    const int tid = threadIdx.x;
    const int b   = blockIdx.x >> 4;
    const int h0  = (blockIdx.x & 15) << 3;
    const float dt2 = 0.0005f;

    // stage ST: 128 rows (c*16+hh) x 32 blk4, 8/thread; zeros outside
    #pragma unroll
    for (int m = 0; m < 8; ++m) {
        const int task = tid + 512 * m;
        const int r = task >> 5, b4 = task & 31;
        const int c = r >> 4, hh = r & 15;
        const int gh = h0 - 4 + hh;
        float4 v = make_float4(0.f, 0.f, 0.f, 0.f);
        if (gh >= 0 && gh < S_) v = *(const float4*)&u0[((b * 8 + c) * S_ + gh) * S_ + 4 * b4];
        *(float4*)&sP[ST0 + swad4(r, b4)] = v;
    }
    __syncthreads();
    // mix0 in place on ST: 2048 pts, 4/thread
    {
        float M[64];
        #pragma unroll
        for (int i = 0; i < 64; ++i) M[i] = cm[i];
        #pragma unroll
        for (int m = 0; m < 4; ++m) {
            const int p = tid + 512 * m;
            const int hh = p >> 7, w = p & 127;
            float v[8], o[8];
            #pragma unroll
            for (int c = 0; c < 8; ++c) v[c] = sP[ST0 + swadw(c * 16 + hh, w)];
            #pragma unroll
            for (int dd = 0; dd < 8; ++dd) {
                float a = 0.f;
                #pragma unroll
                for (int c = 0; c < 8; ++c) a = fmaf(M[dd * 8 + c], v[c], a);
                o[dd] = a;
            }
            #pragma unroll
            for (int c = 0; c < 8; ++c) sP[ST0 + swadw(c * 16 + hh, w)] = o[c];
        }
    }
    __syncthreads();
    // x@0 in place on ST: 128 rows x 16 runs, 4/thread; raw ab (one-time)
    {
        float xh[4][8];
        #pragma unroll
        for (int m = 0; m < 4; ++m) {
            const int r  = (tid & 31) + 32 * m;
            const int wr = tid >> 5;
            const int w0 = wr * 8;
            const int c = r >> 4, hh = r & 15;
            const int gh = h0 - 4 + hh;
            const bool rowin = (gh >= 0 && gh < S_);
            float f[16];
            #pragma unroll
            for (int i = 0; i < 4; ++i) {
                const int bb4 = 2 * wr - 1 + i;
                if (bb4 >= 0 && bb4 < 32) {
                    const float4 va = *(const float4*)&sP[ST0 + swad4(r, bb4)];
                    f[4*i+0]=va.x; f[4*i+1]=va.y; f[4*i+2]=va.z; f[4*i+3]=va.w;
                } else {
                    f[4*i+0]=f[4*i+1]=f[4*i+2]=f[4*i+3]=0.f;
                }
            }
            float e[12], g[12];
            #pragma unroll
            for (int j = 0; j < 12; ++j) {
                const int wj = w0 - 2 + j;
                const bool win = (wj >= 0 && wj < S_);
                float co = 0.f;
                if (rowin && win) {
                    float al = ab[(c * S_ + gh) * S_ + wj];
                    co = fminf(fmaxf(al, EPSF), 10.f) * 0.0005f;
                }
                const float nb = (wj == 0 || wj == S_ - 1) ? 1.f : 2.f;
                const float rb = __builtin_amdgcn_rcpf(fmaf(nb, co, 1.f) + EPSF);
                e[j] = rb * f[j + 2]; g[j] = rb * co;
            }
            jrunN<12>(e, g, xh[m]);
        }
        __syncthreads();
        #pragma unroll
        for (int m = 0; m < 4; ++m) {
            const int r  = (tid & 31) + 32 * m;
            const int wr = tid >> 5;
            *(float4*)&sP[ST0 + swad4(r, 2 * wr)]     = make_float4(xh[m][0], xh[m][1], xh[m][2], xh[m][3]);
            *(float4*)&sP[ST0 + swad4(r, 2 * wr + 1)] = make_float4(xh[m][4], xh[m][5], xh[m][6], xh[m][7]);
        }
    }
    __syncthreads();
    // Y-A raw @ty=1dt2: 16-in (ST) -> 12-out -> P
    {
        const int c = tid >> 6, wp = tid & 63, wb = 2 * wp;
        float o2[2][12];
        #pragma unroll
        for (int s = 0; s < 2; ++s) {
            float e[16], g[16];
            #pragma unroll
            for (int hh = 0; hh < 16; ++hh) {
                const int gh = h0 - 4 + hh;
                const bool inr = (gh >= 0 && gh < S_);
                const int ghc = inr ? gh : 0;
                const int r = c * 16 + hh;
                const float2 d2 = *(const float2*)&sP[ST0 + r * 128 +
                                    (((wp >> 1) ^ (r & 31)) << 2) + 2 * (wp & 1)];
                const float dv = s ? d2.y : d2.x;
                const float2 b2 = *(const float2*)&bb[(c * S_ + ghc) * S_ + wb];
                const float2 t2 = *(const float2*)&btc[(c * S_ + ghc) * S_ + wb];
                float be = fmaf(s ? t2.y : t2.x, 1 * dt2, s ? b2.y : b2.x);
                be = fminf(fmaxf(be, EPSF), 10.f);
                const float co = inr ? be * 0.001f : 0.f;
                const float nb = (gh == 0 || gh == S_ - 1) ? 1.f : 2.f;
                const float rb = __builtin_amdgcn_rcpf(fmaf(nb, co, 1.f) + EPSF);
                e[hh] = rb * dv; g[hh] = rb * co;
            }
            jrunN<16>(e, g, o2[s]);
        }
        #pragma unroll
        for (int i = 0; i < 12; ++i) {
            const int r = c * 12 + i;
            *(float2*)&sP[P0 + r * 128 + (((wp >> 1) ^ (r & 31)) << 2) + 2 * (wp & 1)]
                = make_float2(o2[0][i], o2[1][i]);
        }
    }
    __syncthreads();   // ST dead; C-A below clobbers its tail
    // C-A raw @tx=2dt2: 96 rows x 32 blk4, 6/thread -> packed into C
    #pragma unroll
    for (int m = 0; m < 6; ++m) {
        const int task = tid + 512 * m;
        const int r = task >> 5, b4 = task & 31;
        const int c = r / 12, ha = r - c * 12;
        int gh = h0 - 2 + ha; gh = gh < 0 ? 0 : (gh >= S_ ? S_ - 1 : gh);
        const float4 a4 = *(const float4*)&ab[(c * S_ + gh) * S_ + 4 * b4];
        const float4 t4 = *(const float4*)&atc[(c * S_ + gh) * S_ + 4 * b4];
        uint pk[4];
        #pragma unroll
        for (int l = 0; l < 4; ++l) {
            const int w = 4 * b4 + l;
            const float av = l == 0 ? a4.x : (l == 1 ? a4.y : (l == 2 ? a4.z : a4.w));
            const float tv = l == 0 ? t4.x : (l == 1 ? t4.y : (l == 2 ? t4.z : t4.w));
            float al = fminf(fmaxf(fmaf(tv, 2 * dt2, av), EPSF), 10.f);
            const float co = al * 0.0005f;
            const float nb = (w == 0 || w == S_ - 1) ? 1.f : 2.f;
            const float rb = __builtin_amdgcn_rcpf(fmaf(nb, co, 1.f) + EPSF);
            __half2 hp = __floats2half2_rn(rb * co, rb - 1.f);
            pk[l] = *reinterpret_cast<uint*>(&hp);
        }
        *(float4*)&sP[C0 + swad4(r, b4)] = make_float4(
            __uint_as_float(pk[0]), __uint_as_float(pk[1]),
            __uint_as_float(pk[2]), __uint_as_float(pk[3]));
    }
    __syncthreads();
    // X1-A, mix-A, X2-A (identical to pairS)
    #pragma unroll
    for (int m = 0; m < 3; ++m) {
        const int r  = (tid & 31) + 32 * m;
        const int wr = tid >> 5;
        float f[16]; uint cb[16];
        TAPS_GATHER(P0, f, cb)
        float e[12], g[12];
        #pragma unroll
        for (int j = 0; j < 12; ++j) {
            uint c_ = cb[j + 2];
            const float2 fc = __half22float2(*reinterpret_cast<__half2*>(&c_));
            e[j] = (1.f + fc.y) * f[j + 2];
            g[j] = fc.x;
        }
        float o[8]; jrunN<12>(e, g, o);
        *(float4*)&sP[Q0 + swad4(r, 2 * wr)]     = make_float4(o[0], o[1], o[2], o[3]);
        *(float4*)&sP[Q0 + swad4(r, 2 * wr + 1)] = make_float4(o[4], o[5], o[6], o[7]);
    }
    __syncthreads();
    {
        float M[64];
        #pragma unroll
        for (int i = 0; i < 64; ++i) M[i] = cm[i];
        #pragma unroll
        for (int m = 0; m < 3; ++m) {
            const int p = tid + 512 * m;
            const int ha = p >> 7, w = p & 127;
            float v[8], o[8];
            #pragma unroll
            for (int c = 0; c < 8; ++c) v[c] = sP[Q0 + swadw(c * 12 + ha, w)];
            #pragma unroll
            for (int dd = 0; dd < 8; ++dd) {
                float a = 0.f;
                #pragma unroll
                for (int c = 0; c < 8; ++c) a = fmaf(M[dd * 8 + c], v[c], a);
                o[dd] = a;
            }
            #pragma unroll
            for (int c = 0; c < 8; ++c) sP[Q0 + swadw(c * 12 + ha, w)] = o[c];
        }
    }
    __syncthreads();
    #pragma unroll
    for (int m = 0; m < 3; ++m) {
        const int r  = (tid & 31) + 32 * m;
        const int wr = tid >> 5;
        float f[16]; uint cb[16];
        TAPS_GATHER(Q0, f, cb)
        float e[12], g[12];
        #pragma unroll
        for (int j = 0; j < 12; ++j) {
            uint c_ = cb[j + 2];
            const float2 fc = __half22float2(*reinterpret_cast<__half2*>(&c_));
            e[j] = (1.f + fc.y) * f[j + 2];
            g[j] = fc.x;
        }
        float o[8]; jrunN<12>(e, g, o);
        *(float4*)&sP[P0 + swad4(r, 2 * wr)]     = make_float4(o[0], o[1], o[2], o[3]);
        *(float4*)&sP[P0 + swad4(r, 2 * wr + 1)] = make_float4(o[4], o[5], o[6], o[7]);
    }
    __syncthreads();
    // Y-B raw @ty=3dt2: 12-in (P) -> 8-out -> Q[0,64)
    {
        const int c = tid >> 6, wp = tid & 63, wb = 2 * wp;
        float o2[2][8];
        #pragma unroll
        for (int s = 0; s < 2; ++s) {
            float e[12], g[12];
            #pragma unroll
            for (int hh = 0; hh < 12; ++hh) {
                const int gh = h0 - 2 + hh;
                const bool inr = (gh >= 0 && gh < S_);
                const int ghc = inr ? gh : 0;
                const int r = c * 12 + hh;
                const float2 d2 = *(const float2*)&sP[P0 + r * 128 +
                                    (((wp >> 1) ^ (r & 31)) << 2) + 2 * (wp & 1)];
                const float dv = s ? d2.y : d2.x;
                const float2 b2 = *(const float2*)&bb[(c * S_ + ghc) * S_ + wb];
                const float2 t2 = *(const float2*)&btc[(c * S_ + ghc) * S_ + wb];
                float be = fmaf(s ? t2.y : t2.x, 3 * dt2, s ? b2.y : b2.x);
                be = fminf(fmaxf(be, EPSF), 10.f);
                const float co = inr ? be * 0.001f : 0.f;
                const float nb = (gh == 0 || gh == S_ - 1) ? 1.f : 2.f;
                const float rb = __builtin_amdgcn_rcpf(fmaf(nb, co, 1.f) + EPSF);
                e[hh] = rb * dv; g[hh] = rb * co;
            }
            jrunN<12>(e, g, o2[s]);
        }
        #pragma unroll
        for (int i = 0; i < 8; ++i) {
            const int r = c * 8 + i;
            *(float2*)&sP[Q0 + r * 128 + (((wp >> 1) ^ (r & 31)) << 2) + 2 * (wp & 1)]
                = make_float2(o2[0][i], o2[1][i]);
        }
    }
    // C-B raw @tx=4dt2: 64 rows x 32 blk4, 4/thread
    #pragma unroll
    for (int m = 0; m < 4; ++m) {
        const int task = tid + 512 * m;
        const int r = task >> 5, b4 = task & 31;
        const int c = r >> 3, ho = r & 7;
        const int gh = h0 + ho;
        const float4 a4 = *(const float4*)&ab[(c * S_ + gh) * S_ + 4 * b4];
        const float4 t4 = *(const float4*)&atc[(c * S_ + gh) * S_ + 4 * b4];
        uint pk[4];
        #pragma unroll
        for (int l = 0; l < 4; ++l) {
            const int w = 4 * b4 + l;
            const float av = l == 0 ? a4.x : (l == 1 ? a4.y : (l == 2 ? a4.z : a4.w));
            const float tv = l == 0 ? t4.x : (l == 1 ? t4.y : (l == 2 ? t4.z : t4.w));
            float al = fminf(fmaxf(fmaf(tv, 4 * dt2, av), EPSF), 10.f);
            const float co = al * 0.0005f;
            const float nb = (w == 0 || w == S_ - 1) ? 1.f : 2.f;
            const float rb = __builtin_amdgcn_rcpf(fmaf(nb, co, 1.f) + EPSF);
            __half2 hp = __floats2half2_rn(rb * co, rb - 1.f);
            pk[l] = *reinterpret_cast<uint*>(&hp);
        }
        *(float4*)&sP[C0 + swad4(r, b4)] = make_float4(
            __uint_as_float(pk[0]), __uint_as_float(pk[1]),
            __uint_as_float(pk[2]), __uint_as_float(pk[3]));
    }
    __syncthreads();
    // X1-B, park, mix-B, X2-B -> fp16 ud
    float rbk[2][12], gk[2][12], xo[2][8];
    #pragma unroll
    for (int m = 0; m < 2; ++m) {
        const int r  = tid & 63;
        const int wr = (tid >> 6) + 8 * m;
        float f[16]; uint cb[16];
        TAPS_GATHER(Q0, f, cb)
        float e[12];
        #pragma unroll
        for (int j = 0; j < 12; ++j) {
            uint c_ = cb[j + 2];
            const float2 fc = __half22float2(*reinterpret_cast<__half2*>(&c_));
            rbk[m][j] = 1.f + fc.y; gk[m][j] = fc.x;
            e[j] = rbk[m][j] * f[j + 2];
        }
        jrunN<12>(e, gk[m], xo[m]);
    }
    #pragma unroll
    for (int m = 0; m < 2; ++m) {
        const int r  = tid & 63;
        const int wr = (tid >> 6) + 8 * m;
        *(float4*)&sP[P0 + swad4(r, 2 * wr)]     = make_float4(xo[m][0], xo[m][1], xo[m][2], xo[m][3]);
        *(float4*)&sP[P0 + swad4(r, 2 * wr + 1)] = make_float4(xo[m][4], xo[m][5], xo[m][6], xo[m][7]);
    }
    __syncthreads();
    {
        float M[64];
        #pragma unroll
        for (int i = 0; i < 64; ++i) M[i] = cm[i];
        #pragma unroll
        for (int m = 0; m < 2; ++m) {
            const int p = tid + 512 * m;
            const int ho = p >> 7, w = p & 127;
            float v[8], o[8];
            #pragma unroll
            for (int c = 0; c < 8; ++c) v[c] = sP[P0 + swadw(c * 8 + ho, w)];
            #pragma unroll
            for (int dd = 0; dd < 8; ++dd) {
                float a = 0.f;
                #pragma unroll
                for (int c = 0; c < 8; ++c) a = fmaf(M[dd * 8 + c], v[c], a);
                o[dd] = a;
            }
            #pragma unroll
            for (int c = 0; c < 8; ++c) sP[P0 + swadw(c * 8 + ho, w)] = o[c];
        }
    }
    __syncthreads();
    #pragma unroll
    for (int m = 0; m < 2; ++m) {
        const int r  = tid & 63;
        const int wr = (tid >> 6) + 8 * m;
        const int c = r >> 3, ho = r & 7;
        float f[16];
        #pragma unroll
        for (int i = 0; i < 4; ++i) {
            const int bb4 = 2 * wr - 1 + i;
            if (bb4 >= 0 && bb4 < 32) {
                const float4 va = *(const float4*)&sP[P0 + swad4(r, bb4)];
                f[4*i+0]=va.x; f[4*i+1]=va.y; f[4*i+2]=va.z; f[4*i+3]=va.w;
            } else {
                f[4*i+0]=f[4*i+1]=f[4*i+2]=f[4*i+3]=0.f;
            }
        }
        float e[12];
        #pragma unroll
        for (int j = 0; j < 12; ++j) e[j] = rbk[m][j] * f[j + 2];
        float o[8]; jrunN<12>(e, gk[m], o);
        __half2 q0 = __floats2half2_rn(o[0], o[1]);
        __half2 q1 = __floats2half2_rn(o[2], o[3]);
        __half2 q2 = __floats2half2_rn(o[4], o[5]);
        __half2 q3 = __floats2half2_rn(o[6], o[7]);
        uint4 pk;
        pk.x = *reinterpret_cast<uint*>(&q0);
        pk.y = *reinterpret_cast<uint*>(&q1);
        pk.z = *reinterpret_cast<uint*>(&q2);
        pk.w = *reinterpret_cast<uint*>(&q3);
        *(uint4*)&ud[((b * 8 + c) * S_ + h0 + ho) * S_ + wr * 8] = pk;
    }

    // epilogue: write packed coeff fields for steps 2..9 (1 pt/thread)
    {
        const int idx = blockIdx.x * 512 + tid;
        const float abv = ab[idx], atv = atc[idx], bbv = bb[idx], btv = btc[idx];
        const int w = idx & 127, h = (idx >> 7) & 127;
        const float nbY = (h == 0 || h == S_ - 1) ? 1.f : 2.f;
        const float nbX = (w == 0 || w == S_ - 1) ? 1.f : 2.f;
        #pragma unroll
        for (int k = 2; k < 10; ++k) {
            float be = fminf(fmaxf(fmaf(btv, (2 * k + 1) * dt2, bbv), EPSF), 10.f);
            float co = be * 0.001f;
            float rb = __builtin_amdgcn_rcpf(fmaf(nbY, co, 1.f) + EPSF);
            cf[k * CSS + idx] = __floats2half2_rn(rb * co, rb - 1.f);
            float al = fminf(fmaxf(fmaf(atv, (2 * k + 2) * dt2, abv), EPSF), 10.f);
            co = al * 0.0005f;
            rb = __builtin_amdgcn_rcpf(fmaf(nbX, co, 1.f) + EPSF);
            cf[(10 + k) * CSS + idx] = __floats2half2_rn(rb * co, rb - 1.f);
        }
    }
}

extern "C" void kernel_launch(void* const* d_in, const int* in_sizes, int n_in,
                              void* d_out, int out_size, void* d_ws, size_t ws_size,
                              hipStream_t stream) {
    const float* u_in = (const float*)d_in[0];
    const float* ab   = (const float*)d_in[1];
    const float* bbta = (const float*)d_in[2];
    const float* atc  = (const float*)d_in[3];
    const float* btc  = (const float*)d_in[4];
    const float* cm   = (const float*)d_in[5];
    float* uo = (float*)d_out;
    __half*  h1 = (__half*)d_ws;                           // 4.2MB
    __half*  h2 = (__half*)((char*)d_ws + (8u << 20));     // 4.2MB
    __half2* cf = (__half2*)((char*)d_ws + (16u << 20));   // 10.5MB

    const dim3 g(256), blk(512);
    // head2: steps 0,1 -> h1 (state after leading-x of step 2) + cf fields
    head2_kernel<<<g, blk, 0, stream>>>(u_in, h1, ab, atc, bbta, btc, cm, cf);
    // pairs: (2,3) (4,5) (6,7) (8,9-final)
    pairS_kernel<false><<<g, blk, 0, stream>>>(h1, h2, cf + 2 * CSS, cf + 12 * CSS,
                                               cf + 3 * CSS, cf + 13 * CSS, cm);
    pairS_kernel<false><<<g, blk, 0, stream>>>(h2, h1, cf + 4 * CSS, cf + 14 * CSS,
                                               cf + 5 * CSS, cf + 15 * CSS, cm);
    pairS_kernel<false><<<g, blk, 0, stream>>>(h1, h2, cf + 6 * CSS, cf + 16 * CSS,
                                               cf + 7 * CSS, cf + 17 * CSS, cm);
    pairS_kernel<true><<<g, blk, 0, stream>>>(h2, uo, cf + 8 * CSS, cf + 18 * CSS,
                                              cf + 9 * CSS, cf + 19 * CSS, cm);
}

// Round 13
// 156.081 us; speedup vs baseline: 1.0507x; 1.0507x over previous
//
#include <hip/hip_runtime.h>
#include <hip/hip_fp16.h>

// ADI diffusion B=16, C=8, S=128, 10 steps. Round 22: r11 base (152.7us,
// best) + surgical cuts. (1) g-only half coeffs: rb-1 == -nb*g exactly
// (eps<=1e-6), so store just g -> coef traffic halves, rb reconstructed by
// one fma with wave-uniform nb. (2) head ported to the proven swizzled
// b128 phase patterns. (3) stepS Y-coeff loads uint2->uint. Pair fusion is
// permanently closed (r7 wash, r10/r12 losses: lead-step redundancy 1.5x).

constexpr int S_  = 128;
constexpr float EPSF = 1e-6f;
constexpr int CSS = 8 * 128 * 128;  // points per coeff field

// stepS LDS: 3 x 64 rows x 128 floats = 96 KB
constexpr int SA = 0;
constexpr int SB = 64 * 128;
constexpr int SC = 128 * 128;
constexpr int SPOOL = 192 * 128;
// head LDS: A 64 rows @0, ST 96 rows @96 (B aliases ST rows 96..160), C @192
constexpr int HA  = 0;
constexpr int HST = 96 * 128;
constexpr int HB  = 96 * 128;
constexpr int HC  = 192 * 128;
constexpr int HPOOL = 256 * 128;    // 128 KB

__device__ __forceinline__ int swad4(int r, int b4) {
    return r * 128 + (((b4) ^ (r & 31)) << 2);
}
__device__ __forceinline__ int swadw(int r, int w) {
    return r * 128 + ((((w) >> 2) ^ (r & 31)) << 2) + ((w) & 3);
}

template <int N>
__device__ __forceinline__ void jrunN(const float (&e)[N], const float (&g)[N],
                                      float (&o)[N - 4]) {
    // Jacobi-2 == fixed 5-point formula, stencil radius 2 per output.
    float x1[N];
    #pragma unroll
    for (int i = 1; i <= N - 2; ++i) x1[i] = fmaf(g[i], e[i - 1] + e[i + 1], e[i]);
    #pragma unroll
    for (int i = 2; i <= N - 3; ++i) o[i - 2] = fmaf(g[i], x1[i - 1] + x1[i + 1], e[i]);
}

// gather 16 values from region RA and 16 g-floats from region RC, run (r,wr)
#define TAPS2(RA, RC, f, gt)                                                   \
    {                                                                          \
        _Pragma("unroll")                                                      \
        for (int i_ = 0; i_ < 4; ++i_) {                                       \
            const int bb_ = 2 * wr - 1 + i_;                                   \
            if (bb_ >= 0 && bb_ < 32) {                                        \
                const float4 va_ = *(const float4*)&sP[(RA) + swad4(r, bb_)];  \
                const float4 vc_ = *(const float4*)&sP[(RC) + swad4(r, bb_)];  \
                f[4*i_+0]=va_.x; f[4*i_+1]=va_.y; f[4*i_+2]=va_.z; f[4*i_+3]=va_.w; \
                gt[4*i_+0]=vc_.x; gt[4*i_+1]=vc_.y; gt[4*i_+2]=vc_.z; gt[4*i_+3]=vc_.w; \
            } else {                                                           \
                f[4*i_+0]=f[4*i_+1]=f[4*i_+2]=f[4*i_+3]=0.f;                   \
                gt[4*i_+0]=gt[4*i_+1]=gt[4*i_+2]=gt[4*i_+3]=0.f;               \
            }                                                                  \
        }                                                                      \
    }

// ---- coef: fields 0..9 = g_Y@t_y(k); 10..19 = g_X@t_x(k). Half, g only.
__global__ __launch_bounds__(256) void coef_kernel(
    const float* __restrict__ ab, const float* __restrict__ atc,
    const float* __restrict__ bb, const float* __restrict__ btc,
    __half* __restrict__ cg)
{
    for (int gc = blockIdx.x * 256 + threadIdx.x; gc < CSS; gc += gridDim.x * 256) {
        const int w = gc & 127, h = (gc >> 7) & 127;
        const float abv = ab[gc], atv = atc[gc], bbv = bb[gc], btv = btc[gc];
        const float nbY = (h == 0 || h == S_ - 1) ? 1.f : 2.f;
        const float nbX = (w == 0 || w == S_ - 1) ? 1.f : 2.f;
        #pragma unroll
        for (int k = 0; k < 10; ++k) {
            float be = fminf(fmaxf(fmaf(btv, (2 * k + 1) * 0.0005f, bbv), EPSF), 10.f);
            float co = be * 0.001f;
            float rb = __builtin_amdgcn_rcpf(fmaf(nbY, co, 1.f) + EPSF);
            cg[k * CSS + gc] = __float2half(rb * co);
            float al = fminf(fmaxf(fmaf(atv, (2 * k + 2) * 0.0005f, abv), EPSF), 10.f);
            co = al * 0.0005f;
            rb = __builtin_amdgcn_rcpf(fmaf(nbX, co, 1.f) + EPSF);
            cg[(10 + k) * CSS + gc] = __float2half(rb * co);
        }
    }
}

// ---- head: step 0 (mix0 + x@0 raw + Y + x|mix|x), swizzled phases ----
__global__ __launch_bounds__(512) void head_kernel(
    const float* __restrict__ u0, __half* __restrict__ ud,
    const float* __restrict__ ab, const __half* __restrict__ cgy,
    const __half* __restrict__ cgx, const float* __restrict__ cm)
{
    __shared__ __align__(16) float sP[HPOOL];
    const int tid = threadIdx.x;
    const int b   = blockIdx.x >> 4;
    const int h0  = (blockIdx.x & 15) << 3;

    // stage 96 rows (c*12+hh) x 32 b4 into ST; zeros outside domain
    #pragma unroll
    for (int m = 0; m < 6; ++m) {
        const int task = tid + 512 * m;
        const int r = task >> 5, b4 = task & 31;
        const int c = r / 12, hh = r - c * 12;
        const int gh = h0 - 2 + hh;
        float4 v = make_float4(0.f, 0.f, 0.f, 0.f);
        if (gh >= 0 && gh < S_) v = *(const float4*)&u0[((b * 8 + c) * S_ + gh) * S_ + 4 * b4];
        *(float4*)&sP[HST + swad4(r, b4)] = v;
    }
    __syncthreads();
    {   // mix0 in place on ST: 1536 pts, 3/thread
        float M[64];
        #pragma unroll
        for (int i = 0; i < 64; ++i) M[i] = cm[i];
        #pragma unroll
        for (int m = 0; m < 3; ++m) {
            const int p = tid + 512 * m;
            const int hh = p >> 7, w = p & 127;
            float v[8], o[8];
            #pragma unroll
            for (int c = 0; c < 8; ++c) v[c] = sP[HST + swadw(c * 12 + hh, w)];
            #pragma unroll
            for (int dd = 0; dd < 8; ++dd) {
                float a = 0.f;
                #pragma unroll
                for (int c = 0; c < 8; ++c) a = fmaf(M[dd * 8 + c], v[c], a);
                o[dd] = a;
            }
            #pragma unroll
            for (int c = 0; c < 8; ++c) sP[HST + swadw(c * 12 + hh, w)] = o[c];
        }
    }
    __syncthreads();
    {   // x@0 in place on ST: 96 rows x 16 runs, 3/thread, raw ab (one-time)
        float xh[3][8];
        #pragma unroll
        for (int m = 0; m < 3; ++m) {
            const int r  = (tid & 31) + 32 * m;
            const int wr = tid >> 5;
            const int w0 = wr * 8;
            const int c = r / 12, hh = r - c * 12;
            const int gh = h0 - 2 + hh;
            const bool rowin = (gh >= 0 && gh < S_);
            float f[16];
            #pragma unroll
            for (int i = 0; i < 4; ++i) {
                const int bb4 = 2 * wr - 1 + i;
                if (bb4 >= 0 && bb4 < 32) {
                    const float4 va = *(const float4*)&sP[HST + swad4(r, bb4)];
                    f[4*i+0]=va.x; f[4*i+1]=va.y; f[4*i+2]=va.z; f[4*i+3]=va.w;
                } else {
                    f[4*i+0]=f[4*i+1]=f[4*i+2]=f[4*i+3]=0.f;
                }
            }
            float e[12], g[12];
            #pragma unroll
            for (int j = 0; j < 12; ++j) {
                const int wj = w0 - 2 + j;
                const bool win = (wj >= 0 && wj < S_);
                float co = 0.f;
                if (rowin && win) {
                    float al = ab[(c * S_ + gh) * S_ + wj];
                    co = fminf(fmaxf(al, EPSF), 10.f) * 0.0005f;
                }
                const float nb = (wj == 0 || wj == S_ - 1) ? 1.f : 2.f;
                const float rb = __builtin_amdgcn_rcpf(fmaf(nb, co, 1.f) + EPSF);
                e[j] = rb * f[j + 2]; g[j] = rb * co;
            }
            jrunN<12>(e, g, xh[m]);
        }
        __syncthreads();
        #pragma unroll
        for (int m = 0; m < 3; ++m) {
            const int r  = (tid & 31) + 32 * m;
            const int wr = tid >> 5;
            *(float4*)&sP[HST + swad4(r, 2 * wr)]     = make_float4(xh[m][0], xh[m][1], xh[m][2], xh[m][3]);
            *(float4*)&sP[HST + swad4(r, 2 * wr + 1)] = make_float4(xh[m][4], xh[m][5], xh[m][6], xh[m][7]);
        }
    }
    __syncthreads();
    // Y: (c, w-pair)/thread; 12-in (ST) -> 8-out -> A
    {
        const int c = tid >> 6, wp = tid & 63, wb = 2 * wp;
        float2 dp[12]; uint dg[12];
        #pragma unroll
        for (int hh = 0; hh < 12; ++hh) {
            const int gh = h0 - 2 + hh;
            const bool inr = (gh >= 0 && gh < S_);
            const int ghc = inr ? gh : 0;
            const int r = c * 12 + hh;
            dp[hh] = *(const float2*)&sP[HST + r * 128 +
                                         (((wp >> 1) ^ (r & 31)) << 2) + 2 * (wp & 1)];
            dg[hh] = *(const uint*)&cgy[(c * S_ + ghc) * S_ + wb];
        }
        float o2[2][8];
        #pragma unroll
        for (int s = 0; s < 2; ++s) {
            float e[12], g[12];
            #pragma unroll
            for (int hh = 0; hh < 12; ++hh) {
                const int gh = h0 - 2 + hh;
                const bool inr = (gh >= 0 && gh < S_);
                uint gb = dg[hh];
                __half2 hg = *reinterpret_cast<__half2*>(&gb);
                float gv = s ? __high2float(hg) : __low2float(hg);
                gv = inr ? gv : 0.f;
                const float nb = (gh == 0 || gh == S_ - 1) ? 1.f : 2.f;
                const float rb = fmaf(-nb, gv, 1.f);
                e[hh] = rb * (s ? dp[hh].y : dp[hh].x);
                g[hh] = gv;
            }
            jrunN<12>(e, g, o2[s]);
        }
        #pragma unroll
        for (int i = 0; i < 8; ++i) {
            const int r = c * 8 + i;
            *(float2*)&sP[HA + r * 128 + (((wp >> 1) ^ (r & 31)) << 2) + 2 * (wp & 1)]
                = make_float2(o2[0][i], o2[1][i]);
        }
    }
    // C: 64 rows x 32 b4, 4/thread (4 halves -> 4 floats g)
    {
        const ushort* cx = (const ushort*)cgx;
        #pragma unroll
        for (int m = 0; m < 4; ++m) {
            const int task = tid + 512 * m;
            const int r = task >> 5, b4 = task & 31;
            const int c = r >> 3, ho = r & 7;
            const uint2 v = *(const uint2*)&cx[(c * S_ + h0 + ho) * S_ + b4 * 4];
            uint lo = v.x, hi = v.y;
            __half2 h0_ = *reinterpret_cast<__half2*>(&lo);
            __half2 h1_ = *reinterpret_cast<__half2*>(&hi);
            *(float4*)&sP[HC + swad4(r, b4)] = make_float4(
                __low2float(h0_), __high2float(h0_), __low2float(h1_), __high2float(h1_));
        }
    }
    __syncthreads();
    // X1: 64 rows x 16 runs, 2/thread; cache rb/g for X2
    float rbk[2][12], gk[2][12], xo[2][8];
    #pragma unroll
    for (int m = 0; m < 2; ++m) {
        const int r  = tid & 63;
        const int wr = (tid >> 6) + 8 * m;
        const int w0 = wr * 8;
        float f[16], gt[16];
        TAPS2(HA, HC, f, gt)
        float e[12];
        #pragma unroll
        for (int j = 0; j < 12; ++j) {
            const int wj = w0 - 2 + j;
            const float nb = (wj == 0 || wj == S_ - 1) ? 1.f : 2.f;
            gk[m][j] = gt[j + 2];
            rbk[m][j] = fmaf(-nb, gt[j + 2], 1.f);
            e[j] = rbk[m][j] * f[j + 2];
        }
        jrunN<12>(e, gk[m], xo[m]);
    }
    // park xo -> B (rows 96..160; ST dead)
    #pragma unroll
    for (int m = 0; m < 2; ++m) {
        const int r  = tid & 63;
        const int wr = (tid >> 6) + 8 * m;
        *(float4*)&sP[HB + swad4(r, 2 * wr)]     = make_float4(xo[m][0], xo[m][1], xo[m][2], xo[m][3]);
        *(float4*)&sP[HB + swad4(r, 2 * wr + 1)] = make_float4(xo[m][4], xo[m][5], xo[m][6], xo[m][7]);
    }
    __syncthreads();
    {   // mix: read B, write A: 1024 pts, 2/thread
        float M[64];
        #pragma unroll
        for (int i = 0; i < 64; ++i) M[i] = cm[i];
        #pragma unroll
        for (int m = 0; m < 2; ++m) {
            const int p = tid + 512 * m;
            const int ho = p >> 7, w = p & 127;
            float v[8], o[8];
            #pragma unroll
            for (int c = 0; c < 8; ++c) v[c] = sP[HB + swadw(c * 8 + ho, w)];
            #pragma unroll
            for (int dd = 0; dd < 8; ++dd) {
                float a = 0.f;
                #pragma unroll
                for (int c = 0; c < 8; ++c) a = fmaf(M[dd * 8 + c], v[c], a);
                o[dd] = a;
            }
            #pragma unroll
            for (int c = 0; c < 8; ++c) sP[HA + swadw(c * 8 + ho, w)] = o[c];
        }
    }
    __syncthreads();
    // X2: A taps + cached coeffs -> fp16 out
    #pragma unroll
    for (int m = 0; m < 2; ++m) {
        const int r  = tid & 63;
        const int wr = (tid >> 6) + 8 * m;
        const int c = r >> 3, ho = r & 7;
        float f[16];
        #pragma unroll
        for (int i = 0; i < 4; ++i) {
            const int bb4 = 2 * wr - 1 + i;
            if (bb4 >= 0 && bb4 < 32) {
                const float4 va = *(const float4*)&sP[HA + swad4(r, bb4)];
                f[4*i+0]=va.x; f[4*i+1]=va.y; f[4*i+2]=va.z; f[4*i+3]=va.w;
            } else {
                f[4*i+0]=f[4*i+1]=f[4*i+2]=f[4*i+3]=0.f;
            }
        }
        float e[12];
        #pragma unroll
        for (int j = 0; j < 12; ++j) e[j] = rbk[m][j] * f[j + 2];
        float o[8]; jrunN<12>(e, gk[m], o);
        __half2 q0 = __floats2half2_rn(o[0], o[1]);
        __half2 q1 = __floats2half2_rn(o[2], o[3]);
        __half2 q2 = __floats2half2_rn(o[4], o[5]);
        __half2 q3 = __floats2half2_rn(o[6], o[7]);
        uint4 pk;
        pk.x = *reinterpret_cast<uint*>(&q0);
        pk.y = *reinterpret_cast<uint*>(&q1);
        pk.z = *reinterpret_cast<uint*>(&q2);
        pk.w = *reinterpret_cast<uint*>(&q3);
        *(uint4*)&ud[((b * 8 + c) * S_ + h0 + ho) * S_ + wr * 8] = pk;
    }
}

// ---- mid/last step: r11 structure, g-only coeffs ----
template <bool LASTK>
__global__ __launch_bounds__(512) void stepS_kernel(
    const __half* __restrict__ us, void* __restrict__ udst_,
    const __half* __restrict__ cgy, const __half* __restrict__ cgx,
    const float* __restrict__ cm)
{
    __shared__ __align__(16) float sP[SPOOL];
    const int tid = threadIdx.x;
    const int b   = blockIdx.x >> 4;
    const int h0  = (blockIdx.x & 15) << 3;

    // ---- Y: (c, w-pair)/thread; 12-in -> 8-out -> A (swz)
    {
        const int c = tid >> 6, wp = tid & 63, wb = 2 * wp;
        uint du[12], dg[12];
        #pragma unroll
        for (int hh = 0; hh < 12; ++hh) {
            const int gh = h0 - 2 + hh;
            const bool inr = (gh >= 0 && gh < S_);
            const int ghc = inr ? gh : 0;
            du[hh] = inr ? *(const uint*)&us[((b * 8 + c) * S_ + ghc) * S_ + wb] : 0u;
            dg[hh] = *(const uint*)&cgy[(c * S_ + ghc) * S_ + wb];
        }
        float o2[2][8];
        #pragma unroll
        for (int s = 0; s < 2; ++s) {
            float e[12], g[12];
            #pragma unroll
            for (int hh = 0; hh < 12; ++hh) {
                const int gh = h0 - 2 + hh;
                const bool inr = (gh >= 0 && gh < S_);
                uint ub = du[hh];
                __half2 hu = *reinterpret_cast<__half2*>(&ub);
                const float dv = s ? __high2float(hu) : __low2float(hu);
                uint gb = dg[hh];
                __half2 hg = *reinterpret_cast<__half2*>(&gb);
                float gv = s ? __high2float(hg) : __low2float(hg);
                gv = inr ? gv : 0.f;
                const float nb = (gh == 0 || gh == S_ - 1) ? 1.f : 2.f;
                const float rb = fmaf(-nb, gv, 1.f);
                e[hh] = rb * dv;
                g[hh] = gv;
            }
            jrunN<12>(e, g, o2[s]);
        }
        #pragma unroll
        for (int i = 0; i < 8; ++i) {
            const int r = c * 8 + i;
            *(float2*)&sP[SA + r * 128 + (((wp >> 1) ^ (r & 31)) << 2) + 2 * (wp & 1)]
                = make_float2(o2[0][i], o2[1][i]);
        }
    }
    // ---- C: 64 rows x 32 b4, 4/thread (4 halves -> 4 floats g)
    {
        const ushort* cx = (const ushort*)cgx;
        #pragma unroll
        for (int m = 0; m < 4; ++m) {
            const int task = tid + 512 * m;
            const int r = task >> 5, b4 = task & 31;
            const int c = r >> 3, ho = r & 7;
            const uint2 v = *(const uint2*)&cx[(c * S_ + h0 + ho) * S_ + b4 * 4];
            uint lo = v.x, hi = v.y;
            __half2 h0_ = *reinterpret_cast<__half2*>(&lo);
            __half2 h1_ = *reinterpret_cast<__half2*>(&hi);
            *(float4*)&sP[SC + swad4(r, b4)] = make_float4(
                __low2float(h0_), __high2float(h0_), __low2float(h1_), __high2float(h1_));
        }
    }
    __syncthreads();

    // ---- X1: 64 rows x 16 runs, 2/thread; cache rb/g for X2
    float rbk[2][12], gk[2][12], xo[2][8];
    #pragma unroll
    for (int m = 0; m < 2; ++m) {
        const int r  = tid & 63;
        const int wr = (tid >> 6) + 8 * m;
        const int w0 = wr * 8;
        float f[16], gt[16];
        TAPS2(SA, SC, f, gt)
        float e[12];
        #pragma unroll
        for (int j = 0; j < 12; ++j) {
            const int wj = w0 - 2 + j;
            const float nb = (wj == 0 || wj == S_ - 1) ? 1.f : 2.f;
            gk[m][j] = gt[j + 2];
            rbk[m][j] = fmaf(-nb, gt[j + 2], 1.f);
            e[j] = rbk[m][j] * f[j + 2];
        }
        jrunN<12>(e, gk[m], xo[m]);
    }

    if (LASTK) {
        float* ud = (float*)udst_;
        #pragma unroll
        for (int m = 0; m < 2; ++m) {
            const int r  = tid & 63;
            const int wr = (tid >> 6) + 8 * m;
            const int c = r >> 3, ho = r & 7;
            float4* dst4 = (float4*)&ud[((b * 8 + c) * S_ + h0 + ho) * S_ + wr * 8];
            dst4[0] = make_float4(xo[m][0], xo[m][1], xo[m][2], xo[m][3]);
            dst4[1] = make_float4(xo[m][4], xo[m][5], xo[m][6], xo[m][7]);
        }
    } else {
        // park xo -> B
        #pragma unroll
        for (int m = 0; m < 2; ++m) {
            const int r  = tid & 63;
            const int wr = (tid >> 6) + 8 * m;
            *(float4*)&sP[SB + swad4(r, 2 * wr)]     = make_float4(xo[m][0], xo[m][1], xo[m][2], xo[m][3]);
            *(float4*)&sP[SB + swad4(r, 2 * wr + 1)] = make_float4(xo[m][4], xo[m][5], xo[m][6], xo[m][7]);
        }
        __syncthreads();
        {   // mix: read B, write A
            float M[64];
            #pragma unroll
            for (int i = 0; i < 64; ++i) M[i] = cm[i];
            #pragma unroll
            for (int m = 0; m < 2; ++m) {
                const int p = tid + 512 * m;
                const int ho = p >> 7, w = p & 127;
                float v[8], o[8];
                #pragma unroll
                for (int c = 0; c < 8; ++c) v[c] = sP[SB + swadw(c * 8 + ho, w)];
                #pragma unroll
                for (int dd = 0; dd < 8; ++dd) {
                    float a = 0.f;
                    #pragma unroll
                    for (int c = 0; c < 8; ++c) a = fmaf(M[dd * 8 + c], v[c], a);
                    o[dd] = a;
                }
                #pragma unroll
                for (int c = 0; c < 8; ++c) sP[SA + swadw(c * 8 + ho, w)] = o[c];
            }
        }
        __syncthreads();
        // X2: A taps + cached coeffs -> fp16 out
        __half* ud = (__half*)udst_;
        #pragma unroll
        for (int m = 0; m < 2; ++m) {
            const int r  = tid & 63;
            const int wr = (tid >> 6) + 8 * m;
            const int c = r >> 3, ho = r & 7;
            float f[16];
            #pragma unroll
            for (int i = 0; i < 4; ++i) {
                const int bb4 = 2 * wr - 1 + i;
                if (bb4 >= 0 && bb4 < 32) {
                    const float4 va = *(const float4*)&sP[SA + swad4(r, bb4)];
                    f[4*i+0]=va.x; f[4*i+1]=va.y; f[4*i+2]=va.z; f[4*i+3]=va.w;
                } else {
                    f[4*i+0]=f[4*i+1]=f[4*i+2]=f[4*i+3]=0.f;
                }
            }
            float e[12];
            #pragma unroll
            for (int j = 0; j < 12; ++j) e[j] = rbk[m][j] * f[j + 2];
            float o[8]; jrunN<12>(e, gk[m], o);
            __half2 q0 = __floats2half2_rn(o[0], o[1]);
            __half2 q1 = __floats2half2_rn(o[2], o[3]);
            __half2 q2 = __floats2half2_rn(o[4], o[5]);
            __half2 q3 = __floats2half2_rn(o[6], o[7]);
            uint4 pk;
            pk.x = *reinterpret_cast<uint*>(&q0);
            pk.y = *reinterpret_cast<uint*>(&q1);
            pk.z = *reinterpret_cast<uint*>(&q2);
            pk.w = *reinterpret_cast<uint*>(&q3);
            *(uint4*)&ud[((b * 8 + c) * S_ + h0 + ho) * S_ + wr * 8] = pk;
        }
    }
}

extern "C" void kernel_launch(void* const* d_in, const int* in_sizes, int n_in,
                              void* d_out, int out_size, void* d_ws, size_t ws_size,
                              hipStream_t stream) {
    const float* u_in = (const float*)d_in[0];
    const float* ab   = (const float*)d_in[1];
    const float* bbta = (const float*)d_in[2];
    const float* atc  = (const float*)d_in[3];
    const float* btc  = (const float*)d_in[4];
    const float* cm   = (const float*)d_in[5];
    float* uo = (float*)d_out;
    __half* h1 = (__half*)d_ws;                           // 4.2MB
    __half* h2 = (__half*)((char*)d_ws + (8u << 20));     // 4.2MB
    __half* cg = (__half*)((char*)d_ws + (16u << 20));    // 5.25MB

    coef_kernel<<<dim3(512), dim3(256), 0, stream>>>(ab, atc, bbta, btc, cg);

    const dim3 g(256), blk(512);
    head_kernel<<<g, blk, 0, stream>>>(u_in, h1, ab, cg + 0 * CSS,
                                       cg + 10 * CSS, cm);
    const __half* s = h1; __half* d = h2;
    for (int k = 1; k <= 8; ++k) {
        stepS_kernel<false><<<g, blk, 0, stream>>>(s, d, cg + k * CSS,
                                                   cg + (10 + k) * CSS, cm);
        const __half* ns = d;
        d = (d == h2) ? h1 : h2;
        s = ns;
    }
    stepS_kernel<true><<<g, blk, 0, stream>>>(s, uo, cg + 9 * CSS,
                                              cg + 19 * CSS, cm);
}